// Round 9
// baseline (616.848 us; speedup 1.0000x reference)
//
#include <hip/hip_runtime.h>
#include <hip/hip_bf16.h>
#include <math.h>

// Video-Swin block, MI355X. Round 8: OUTPUT DTYPE FIX — d_out is FLOAT32
// (rounds 5-7's bit-identical absmax 7.21875 = sqrt(2)*max|x| proved the
// checker reads f32 while we wrote bf16 pairs; all three implementations
// were likely numerically correct). MFMA pipeline from rounds 5/6 retained;
// f32 residual x2 lives in d_out (k_mlp updates in place).
// Geometry: S=16,H=96,W=96,C=96, NH=3, HD=32, win=4x4x4 (N=64), shift=2,2,2
// windows: 2304, L=147456.

#define SCALE 0.17677669529663687f  // 32^-0.5

typedef __attribute__((ext_vector_type(8))) short bf16x8;
typedef __attribute__((ext_vector_type(4))) float f32x4;

__device__ inline unsigned short f2bf(float f) {  // round-to-nearest-even
  unsigned u = __float_as_uint(f);
  unsigned r = u + 0x7FFFu + ((u >> 16) & 1u);
  return (unsigned short)(r >> 16);
}

// ---------------------------------------------------------------------------
// Kernel 0: prologue. Blocks [0,216): pack weights to bf16 (u32 pairs).
// Blocks [216,264): precompute bias[3][64][64] = rpb[relidx[n][m]*3+h].
// wtb layout (shorts): fc1wb[36864] | fc2wb[36864] | qkvwb[27648] | projwb[9216]
// ---------------------------------------------------------------------------
__global__ __launch_bounds__(256) void k_cvt(
    const float* __restrict__ fc1w, const float* __restrict__ fc2w,
    const float* __restrict__ qkvw, const float* __restrict__ projw,
    const int* __restrict__ relidx, const float* __restrict__ rpb,
    unsigned* __restrict__ wtb, float* __restrict__ biasf)
{
  if (blockIdx.x < 216) {
    int i = blockIdx.x * 256 + threadIdx.x;
    if (i >= 55296) return;
    int e = i * 2;
    float lo, hi;
    if (e < 36864)       { lo = fc1w[e];           hi = fc1w[e + 1]; }
    else if (e < 73728)  { lo = fc2w[e - 36864];   hi = fc2w[e - 36864 + 1]; }
    else if (e < 101376) { lo = qkvw[e - 73728];   hi = qkvw[e - 73728 + 1]; }
    else                 { lo = projw[e - 101376]; hi = projw[e - 101376 + 1]; }
    wtb[i] = (unsigned)f2bf(lo) | ((unsigned)f2bf(hi) << 16);
  } else {
    int idx = (blockIdx.x - 216) * 256 + threadIdx.x;   // < 12288
    int h = idx >> 12, rem = idx & 4095;                // rem = n*64+m
    biasf[idx] = rpb[relidx[rem] * 3 + h];
  }
}

// ---------------------------------------------------------------------------
// Kernel 1: per-window  LN1 -> shift-gather -> QKV(MFMA) ->
//           attn(bias+mask+softmax, fp32 scalar, scores in regs) ->
//           proj(MFMA) -> +shortcut => x2 (f32, = d_out)
// LDS: xqo f32[64*97] (aliased: xb bf16 A-frags -> q -> attn-out)
//      kv  f32[64*196] (aliased: raw x (stride 97) -> k|v -> xb2 bf16)
// ---------------------------------------------------------------------------
__global__ __launch_bounds__(256) void k_attn(
    const float* __restrict__ x,
    const float* __restrict__ mask,       // [2304,64,64]
    const float* __restrict__ qkv_b,      // [288]
    const float* __restrict__ proj_b,     // [96]
    const float* __restrict__ n1g, const float* __restrict__ n1b,
    const unsigned short* __restrict__ qkvwb,   // [288*96] bf16
    const unsigned short* __restrict__ projwb,  // [96*96]  bf16
    const float* __restrict__ biasf,      // [3,64,64]
    float* __restrict__ x2)               // [147456,96] f32 (= d_out)
{
  __shared__ float xqo[64 * 97];
  __shared__ float kv[64 * 196];
  __shared__ int   lidx[64];
  __shared__ float mu[64], rsd[64];
  unsigned short* xb  = (unsigned short*)xqo;   // 64 rows x 104 shorts (52 u32)
  unsigned short* xb2 = (unsigned short*)kv;

  const int tid  = threadIdx.x;
  const int wi   = blockIdx.x;
  const int lane = tid & 63;
  const int w    = tid >> 6;
  const int lm   = lane & 15, lg = lane >> 4;

  {  // window decomposition + shift indices (read loc == write loc)
    const int sb  = wi / 576;
    const int rem = wi - sb * 576;
    const int hb  = rem / 24;
    const int wb  = rem - hb * 24;
    if (tid < 64) {
      int ts = tid >> 4, th = (tid >> 2) & 3, tw = tid & 3;
      int so = (sb * 4 + ts + 2) & 15;
      int ho = hb * 4 + th + 2; if (ho >= 96) ho -= 96;
      int wo = wb * 4 + tw + 2; if (wo >= 96) wo -= 96;
      lidx[tid] = (so * 96 + ho) * 96 + wo;
    }
  }
  __syncthreads();

  // Phase B: stage raw rows into kv (stride 97)
  #pragma unroll
  for (int i = 0; i < 24; ++i) {
    int e = tid + i * 256;          // 64*96
    int r = e / 96, c = e - r * 96;
    kv[r * 97 + c] = x[lidx[r] * 96 + c];
  }
  __syncthreads();

  // Phase B2: LN1 stats, 4 lanes per row + shfl reduce
  {
    int r = tid >> 2, qq = tid & 3;
    float s = 0.f, s2 = 0.f;
    #pragma unroll
    for (int k = 0; k < 24; ++k) {
      float v = kv[r * 97 + qq * 24 + k];
      s += v; s2 += v * v;
    }
    s += __shfl_xor(s, 1); s2 += __shfl_xor(s2, 1);
    s += __shfl_xor(s, 2); s2 += __shfl_xor(s2, 2);
    if (qq == 0) {
      float m   = s * (1.0f / 96.0f);
      float var = s2 * (1.0f / 96.0f) - m * m;
      mu[r]  = m;
      rsd[r] = rsqrtf(var + 1e-5f);
    }
  }
  __syncthreads();

  // Phase C: LN1-normalize + bf16-pack into xb (aliases xqo)
  #pragma unroll
  for (int i = 0; i < 12; ++i) {
    int e  = tid + i * 256;          // 64 rows x 48 col-pairs
    int r  = e / 48, c2 = e - r * 48;
    float m = mu[r], rs = rsd[r];
    float a0 = (kv[r * 97 + c2 * 2]     - m) * rs * n1g[c2 * 2]     + n1b[c2 * 2];
    float a1 = (kv[r * 97 + c2 * 2 + 1] - m) * rs * n1g[c2 * 2 + 1] + n1b[c2 * 2 + 1];
    ((unsigned*)xb)[r * 52 + c2] = (unsigned)f2bf(a0) | ((unsigned)f2bf(a1) << 16);
  }
  __syncthreads();

  // Phase D: A-fragments (rows w*16+lm) from xb into regs
  bf16x8 af[3];
  #pragma unroll
  for (int ks = 0; ks < 3; ++ks)
    af[ks] = *(const bf16x8*)&xb[(w * 16 + lm) * 104 + ks * 32 + lg * 8];
  __syncthreads();   // xb consumed before q-stores overwrite xqo

  // Phase E: QKV MFMA. Wave w: rows [16w,16w+16), all 288 cols.
  #pragma unroll
  for (int nt = 0; nt < 18; ++nt) {
    const int j = nt * 16 + lm;
    bf16x8 b0 = *(const bf16x8*)&qkvwb[j * 96 + 0  + lg * 8];
    bf16x8 b1 = *(const bf16x8*)&qkvwb[j * 96 + 32 + lg * 8];
    bf16x8 b2 = *(const bf16x8*)&qkvwb[j * 96 + 64 + lg * 8];
    f32x4 acc = {0.f, 0.f, 0.f, 0.f};
    acc = __builtin_amdgcn_mfma_f32_16x16x32_bf16(af[0], b0, acc, 0, 0, 0);
    acc = __builtin_amdgcn_mfma_f32_16x16x32_bf16(af[1], b1, acc, 0, 0, 0);
    acc = __builtin_amdgcn_mfma_f32_16x16x32_bf16(af[2], b2, acc, 0, 0, 0);
    const float bias = qkv_b[j];
    #pragma unroll
    for (int qq = 0; qq < 4; ++qq) {
      const int r2 = w * 16 + lg * 4 + qq;
      float val = acc[qq] + bias;
      if (j < 96)       xqo[r2 * 97 + j] = val * SCALE;       // q (scaled)
      else if (j < 192) kv[r2 * 196 + (j - 96)] = val;        // k
      else              kv[r2 * 196 + 96 + (j - 192)] = val;  // v
    }
  }
  __syncthreads();

  // Phase F: scalar fp32 attention core. thread t<192: head=t>>6, row r=t&63.
  if (tid < 192) {
    const int head = tid >> 6;
    const int r    = tid & 63;
    const int hoff = head * 32;
    float q[32];
    #pragma unroll
    for (int d = 0; d < 32; ++d) q[d] = xqo[r * 97 + hoff + d];

    float s_reg[64];
    const float4* mrow = (const float4*)(mask + (wi * 64 + r) * 64);
    const float4* brow = (const float4*)(biasf + head * 4096 + r * 64);
    float mx = -1e30f;
    #pragma unroll
    for (int m4 = 0; m4 < 16; ++m4) {
      float4 mk = mrow[m4];
      float4 bi = brow[m4];
      float bs[4] = { mk.x + bi.x, mk.y + bi.y, mk.z + bi.z, mk.w + bi.w };
      #pragma unroll
      for (int u = 0; u < 4; ++u) {
        float acc = bs[u];
        #pragma unroll
        for (int dc = 0; dc < 8; ++dc) {
          float4 k4 = *(const float4*)&kv[(m4 * 4 + u) * 196 + hoff + dc * 4];
          acc += q[dc*4+0]*k4.x + q[dc*4+1]*k4.y + q[dc*4+2]*k4.z + q[dc*4+3]*k4.w;
        }
        s_reg[m4 * 4 + u] = acc;
        mx = fmaxf(mx, acc);
      }
    }
    float sum = 0.f;
    #pragma unroll
    for (int m = 0; m < 64; ++m) {
      float e = __expf(s_reg[m] - mx);
      s_reg[m] = e;
      sum += e;
    }
    float inv = 1.0f / sum;

    float4 o[8];
    #pragma unroll
    for (int dc = 0; dc < 8; ++dc) o[dc] = make_float4(0.f, 0.f, 0.f, 0.f);
    #pragma unroll
    for (int m = 0; m < 64; ++m) {
      float p = s_reg[m];
      #pragma unroll
      for (int dc = 0; dc < 8; ++dc) {
        float4 v4 = *(const float4*)&kv[m * 196 + 96 + hoff + dc * 4];
        o[dc].x += p * v4.x; o[dc].y += p * v4.y;
        o[dc].z += p * v4.z; o[dc].w += p * v4.w;
      }
    }
    #pragma unroll
    for (int dc = 0; dc < 8; ++dc) {
      xqo[r * 97 + hoff + dc * 4 + 0] = o[dc].x * inv;
      xqo[r * 97 + hoff + dc * 4 + 1] = o[dc].y * inv;
      xqo[r * 97 + hoff + dc * 4 + 2] = o[dc].z * inv;
      xqo[r * 97 + hoff + dc * 4 + 3] = o[dc].w * inv;
    }
  }
  __syncthreads();

  // Phase G: bf16-pack attn-out into xb2 (aliases kv)
  #pragma unroll
  for (int i = 0; i < 12; ++i) {
    int e  = tid + i * 256;
    int r  = e / 48, c2 = e - r * 48;
    float a0 = xqo[r * 97 + c2 * 2];
    float a1 = xqo[r * 97 + c2 * 2 + 1];
    ((unsigned*)xb2)[r * 52 + c2] = (unsigned)f2bf(a0) | ((unsigned)f2bf(a1) << 16);
  }
  __syncthreads();

  // Phase H: proj MFMA + bias + shortcut -> x2 (f32, in d_out)
  bf16x8 af2[3];
  #pragma unroll
  for (int ks = 0; ks < 3; ++ks)
    af2[ks] = *(const bf16x8*)&xb2[(w * 16 + lm) * 104 + ks * 32 + lg * 8];

  #pragma unroll
  for (int nt = 0; nt < 6; ++nt) {
    const int j = nt * 16 + lm;
    bf16x8 b0 = *(const bf16x8*)&projwb[j * 96 + 0  + lg * 8];
    bf16x8 b1 = *(const bf16x8*)&projwb[j * 96 + 32 + lg * 8];
    bf16x8 b2 = *(const bf16x8*)&projwb[j * 96 + 64 + lg * 8];
    f32x4 acc = {0.f, 0.f, 0.f, 0.f};
    acc = __builtin_amdgcn_mfma_f32_16x16x32_bf16(af2[0], b0, acc, 0, 0, 0);
    acc = __builtin_amdgcn_mfma_f32_16x16x32_bf16(af2[1], b1, acc, 0, 0, 0);
    acc = __builtin_amdgcn_mfma_f32_16x16x32_bf16(af2[2], b2, acc, 0, 0, 0);
    const float bias = proj_b[j];
    #pragma unroll
    for (int qq = 0; qq < 4; ++qq) {
      const int r2 = w * 16 + lg * 4 + qq;
      const int l  = lidx[r2];
      x2[l * 96 + j] = x[l * 96 + j] + acc[qq] + bias;
    }
  }
}

// ---------------------------------------------------------------------------
// Kernel 2: MFMA MLP, f32 residual input, IN-PLACE on d_out (f32).
// 64 rows/block, 4 waves. fc1: waves split N; fc2: waves split M.
// All x2 reads (LN2 stats, normalize, fc2 residual) precede the only write
// (fc2 epilogue, same thread); blocks own disjoint row ranges.
// ---------------------------------------------------------------------------
__global__ __launch_bounds__(256) void k_mlp(
    float* __restrict__ x2,                     // [147456,96] f32 = d_out
    const float* __restrict__ n2g, const float* __restrict__ n2b,
    const float* __restrict__ fc1b, const float* __restrict__ fc2b,
    const unsigned short* __restrict__ fc1wb,   // [384,96] bf16
    const unsigned short* __restrict__ fc2wb)   // [96,384] bf16
{
  __shared__ unsigned short xnb[64 * 104];
  __shared__ unsigned short hid[64 * 392];
  __shared__ float mu[64], rsd[64];

  const int tid  = threadIdx.x;
  const int R0   = blockIdx.x * 64;
  const int lane = tid & 63;
  const int w    = tid >> 6;
  const int lm   = lane & 15, lg = lane >> 4;

  // LN2 stats: thread (r=tid>>2, qq=tid&3), 24 elems each, shfl reduce
  {
    int r = tid >> 2, qq = tid & 3;
    const float4* p = (const float4*)(x2 + (R0 + r) * 96 + qq * 24);
    float s = 0.f, s2 = 0.f;
    #pragma unroll
    for (int i = 0; i < 6; ++i) {
      float4 v = p[i];
      s  += v.x + v.y + v.z + v.w;
      s2 += v.x*v.x + v.y*v.y + v.z*v.z + v.w*v.w;
    }
    s += __shfl_xor(s, 1); s2 += __shfl_xor(s2, 1);
    s += __shfl_xor(s, 2); s2 += __shfl_xor(s2, 2);
    if (qq == 0) {
      float m   = s * (1.0f / 96.0f);
      float var = s2 * (1.0f / 96.0f) - m * m;
      mu[r]  = m;
      rsd[r] = rsqrtf(var + 1e-5f);
    }
  }
  __syncthreads();

  // normalize + bf16-pack into xnb
  #pragma unroll
  for (int i = 0; i < 12; ++i) {
    int e  = tid + i * 256;
    int r  = e / 48, c2 = e - r * 48;
    float2 v = *(const float2*)(x2 + (R0 + r) * 96 + c2 * 2);
    float m = mu[r], rs = rsd[r];
    float a0 = (v.x - m) * rs * n2g[c2 * 2]     + n2b[c2 * 2];
    float a1 = (v.y - m) * rs * n2g[c2 * 2 + 1] + n2b[c2 * 2 + 1];
    ((unsigned*)xnb)[r * 52 + c2] = (unsigned)f2bf(a0) | ((unsigned)f2bf(a1) << 16);
  }
  __syncthreads();

  // fc1 (+bias, exact GELU) -> hid bf16. Wave w: cols [96w,96w+96), all rows.
  bf16x8 af[4][3];
  #pragma unroll
  for (int mt = 0; mt < 4; ++mt)
    #pragma unroll
    for (int ks = 0; ks < 3; ++ks)
      af[mt][ks] = *(const bf16x8*)&xnb[(mt * 16 + lm) * 104 + ks * 32 + lg * 8];

  #pragma unroll
  for (int nt = 0; nt < 6; ++nt) {
    const int j = w * 96 + nt * 16 + lm;            // hidden col
    bf16x8 b0 = *(const bf16x8*)&fc1wb[j * 96 + 0  + lg * 8];
    bf16x8 b1 = *(const bf16x8*)&fc1wb[j * 96 + 32 + lg * 8];
    bf16x8 b2 = *(const bf16x8*)&fc1wb[j * 96 + 64 + lg * 8];
    const float bias = fc1b[j];
    #pragma unroll
    for (int mt = 0; mt < 4; ++mt) {
      f32x4 acc = {0.f, 0.f, 0.f, 0.f};
      acc = __builtin_amdgcn_mfma_f32_16x16x32_bf16(af[mt][0], b0, acc, 0, 0, 0);
      acc = __builtin_amdgcn_mfma_f32_16x16x32_bf16(af[mt][1], b1, acc, 0, 0, 0);
      acc = __builtin_amdgcn_mfma_f32_16x16x32_bf16(af[mt][2], b2, acc, 0, 0, 0);
      #pragma unroll
      for (int qq = 0; qq < 4; ++qq) {
        float h = acc[qq] + bias;
        float g = h * 0.5f * (1.0f + erff(h * 0.70710678118654752f));
        hid[(mt * 16 + lg * 4 + qq) * 392 + j] = f2bf(g);
      }
    }
  }
  __syncthreads();

  // fc2 (+bias, +residual) -> in-place f32. Wave w: rows [16w,16w+16).
  bf16x8 af2[12];
  #pragma unroll
  for (int ks = 0; ks < 12; ++ks)
    af2[ks] = *(const bf16x8*)&hid[(w * 16 + lm) * 392 + ks * 32 + lg * 8];

  #pragma unroll
  for (int nt = 0; nt < 6; ++nt) {
    const int j = nt * 16 + lm;
    f32x4 acc = {0.f, 0.f, 0.f, 0.f};
    #pragma unroll
    for (int ks = 0; ks < 12; ++ks) {
      bf16x8 b = *(const bf16x8*)&fc2wb[j * 384 + ks * 32 + lg * 8];
      acc = __builtin_amdgcn_mfma_f32_16x16x32_bf16(af2[ks], b, acc, 0, 0, 0);
    }
    const float bias = fc2b[j];
    #pragma unroll
    for (int qq = 0; qq < 4; ++qq) {
      int row = R0 + w * 16 + lg * 4 + qq;
      x2[row * 96 + j] = acc[qq] + bias + x2[row * 96 + j];
    }
  }
}

extern "C" void kernel_launch(void* const* d_in, const int* in_sizes, int n_in,
                              void* d_out, int out_size, void* d_ws, size_t ws_size,
                              hipStream_t stream) {
  const float* x      = (const float*)d_in[0];
  const float* mask   = (const float*)d_in[1];
  const int*   relidx = (const int*)d_in[2];
  const float* qkv_w  = (const float*)d_in[3];
  const float* qkv_b  = (const float*)d_in[4];
  const float* proj_w = (const float*)d_in[5];
  const float* proj_b = (const float*)d_in[6];
  const float* n1g    = (const float*)d_in[7];
  const float* n1b    = (const float*)d_in[8];
  const float* n2g    = (const float*)d_in[9];
  const float* n2b    = (const float*)d_in[10];
  const float* fc1w   = (const float*)d_in[11];
  const float* fc1b   = (const float*)d_in[12];
  const float* fc2w   = (const float*)d_in[13];
  const float* fc2b   = (const float*)d_in[14];
  const float* rpb    = (const float*)d_in[15];

  // ws layout (270,336 B total): wtb bf16 [110592 shorts] | biasf f32 [12288]
  unsigned short* wtb = (unsigned short*)d_ws;                 // 221,184 B
  float* biasf = (float*)((char*)d_ws + 221184);               // 49,152 B
  float* x2 = (float*)d_out;                                   // f32 residual & final out

  k_cvt<<<dim3(264), dim3(256), 0, stream>>>(
      fc1w, fc2w, qkv_w, proj_w, relidx, rpb, (unsigned*)wtb, biasf);
  k_attn<<<dim3(2304), dim3(256), 0, stream>>>(
      x, mask, qkv_b, proj_b, n1g, n1b,
      wtb + 73728 /*qkvwb*/, wtb + 101376 /*projwb*/, biasf, x2);
  k_mlp<<<dim3(2304), dim3(256), 0, stream>>>(
      x2, n2g, n2b, fc1b, fc2b,
      wtb /*fc1wb*/, wtb + 36864 /*fc2wb*/);
}

// Round 10
// 339.493 us; speedup vs baseline: 1.8170x; 1.8170x over previous
//
#include <hip/hip_runtime.h>
#include <hip/hip_bf16.h>
#include <math.h>

// Video-Swin block, MI355X. Round 10: full-MFMA attention core (QK^T + PV via
// 16x16x32 bf16 MFMA, softmax on D-fragments w/ shfl row-reduce, V stored
// transposed, P through per-wave LDS transpose); k_mlp re-tiled to 32 rows/
// block (LDS 31.7KB -> ~5 blocks/CU) with in-register LN2 and tanh-GELU.
// Round-9 baseline 616.8us (k_attn 354: MfmaUtil 1.2%, VALU 22%, occ 11.7%).
// Geometry: S=16,H=96,W=96,C=96, NH=3, HD=32, win=4x4x4 (N=64), shift=2,2,2
// windows: 2304, L=147456.

#define SCALE 0.17677669529663687f  // 32^-0.5

typedef __attribute__((ext_vector_type(8))) short bf16x8;
typedef __attribute__((ext_vector_type(4))) float f32x4;

__device__ inline unsigned short f2bf(float f) {  // round-to-nearest-even
  unsigned u = __float_as_uint(f);
  unsigned r = u + 0x7FFFu + ((u >> 16) & 1u);
  return (unsigned short)(r >> 16);
}

// ---------------------------------------------------------------------------
// Kernel 0: prologue. Blocks [0,216): pack weights to bf16 (u32 pairs).
// Blocks [216,264): precompute bias[3][64][64] = rpb[relidx[n][m]*3+h].
// wtb layout (shorts): fc1wb[36864] | fc2wb[36864] | qkvwb[27648] | projwb[9216]
// ---------------------------------------------------------------------------
__global__ __launch_bounds__(256) void k_cvt(
    const float* __restrict__ fc1w, const float* __restrict__ fc2w,
    const float* __restrict__ qkvw, const float* __restrict__ projw,
    const int* __restrict__ relidx, const float* __restrict__ rpb,
    unsigned* __restrict__ wtb, float* __restrict__ biasf)
{
  if (blockIdx.x < 216) {
    int i = blockIdx.x * 256 + threadIdx.x;
    if (i >= 55296) return;
    int e = i * 2;
    float lo, hi;
    if (e < 36864)       { lo = fc1w[e];           hi = fc1w[e + 1]; }
    else if (e < 73728)  { lo = fc2w[e - 36864];   hi = fc2w[e - 36864 + 1]; }
    else if (e < 101376) { lo = qkvw[e - 73728];   hi = qkvw[e - 73728 + 1]; }
    else                 { lo = projw[e - 101376]; hi = projw[e - 101376 + 1]; }
    wtb[i] = (unsigned)f2bf(lo) | ((unsigned)f2bf(hi) << 16);
  } else {
    int idx = (blockIdx.x - 216) * 256 + threadIdx.x;   // < 12288
    int h = idx >> 12, rem = idx & 4095;                // rem = n*64+m
    biasf[idx] = rpb[relidx[rem] * 3 + h];
  }
}

// ---------------------------------------------------------------------------
// Kernel 1: per-window, 4 waves. All GEMMs incl. QK^T/PV on MFMA.
// Frag conventions (m89-verified, round-9-passed):
//   A: row=lane&15 (+tile), k=8*(lane>>4)+i ;  B: col=lane&15, same k
//   D: col=lane&15, row=4*(lane>>4)+reg
// LDS (61.8 KB -> 2 blocks/CU):
//   qb[64][104]s, kb[64][104]s (bf16 q,k rows), vtb[96][72]s (V transposed),
//   pb[64][72]s (per-wave P transpose buf), xob[64][104]s (LN'd x -> attn out)
// ---------------------------------------------------------------------------
__global__ __launch_bounds__(256) void k_attn(
    const float* __restrict__ x,
    const float* __restrict__ mask,       // [2304,64,64]
    const float* __restrict__ qkv_b,      // [288]
    const float* __restrict__ proj_b,     // [96]
    const float* __restrict__ n1g, const float* __restrict__ n1b,
    const unsigned short* __restrict__ qkvwb,   // [288*96] bf16
    const unsigned short* __restrict__ projwb,  // [96*96]  bf16
    const float* __restrict__ biasf,      // [3,64,64]
    float* __restrict__ x2)               // [147456,96] f32 (= d_out)
{
  __shared__ unsigned short qb_s[64 * 104];
  __shared__ unsigned short kb_s[64 * 104];
  __shared__ unsigned short vtb_s[96 * 72];
  __shared__ unsigned short pb_s[64 * 72];     // wave w: rows [16w,16w+16)
  __shared__ unsigned short xob_s[64 * 104];   // LN'd x (bf16) -> attn-out
  __shared__ int lidx[64];

  const int tid  = threadIdx.x;
  const int wi   = blockIdx.x;
  const int lane = tid & 63;
  const int w    = tid >> 6;
  const int lm   = lane & 15, lg = lane >> 4;

  {  // window decomposition + shift indices (read loc == write loc)
    const int sb  = wi / 576;
    const int rem = wi - sb * 576;
    const int hb  = rem / 24;
    const int wb  = rem - hb * 24;
    if (tid < 64) {
      int ts = tid >> 4, th = (tid >> 2) & 3, tw = tid & 3;
      int so = (sb * 4 + ts + 2) & 15;
      int ho = hb * 4 + th + 2; if (ho >= 96) ho -= 96;
      int wo = wb * 4 + tw + 2; if (wo >= 96) wo -= 96;
      lidx[tid] = (so * 96 + ho) * 96 + wo;
    }
  }
  __syncthreads();

  // Phase B: register staging + LN1 (4 lanes/row, shfl) + bf16 pack into xob.
  // thread (r=tid>>2, qq=tid&3) owns cols [24qq, 24qq+24) of row r.
  {
    const int r = tid >> 2, qq = tid & 3;
    const float4* px = (const float4*)(x + lidx[r] * 96 + qq * 24);
    float4 xr[6];
    float s = 0.f, s2 = 0.f;
    #pragma unroll
    for (int i = 0; i < 6; ++i) {
      xr[i] = px[i];
      s  += xr[i].x + xr[i].y + xr[i].z + xr[i].w;
      s2 += xr[i].x*xr[i].x + xr[i].y*xr[i].y + xr[i].z*xr[i].z + xr[i].w*xr[i].w;
    }
    s += __shfl_xor(s, 1); s2 += __shfl_xor(s2, 1);
    s += __shfl_xor(s, 2); s2 += __shfl_xor(s2, 2);
    float m   = s * (1.0f / 96.0f);
    float var = s2 * (1.0f / 96.0f) - m * m;
    float rs  = rsqrtf(var + 1e-5f);
    const float4* pg = (const float4*)(n1g + qq * 24);
    const float4* pb = (const float4*)(n1b + qq * 24);
    unsigned* dst = (unsigned*)xob_s + r * 52 + qq * 12;
    #pragma unroll
    for (int i = 0; i < 6; ++i) {
      float4 g = pg[i], b = pb[i];
      float a0 = (xr[i].x - m) * rs * g.x + b.x;
      float a1 = (xr[i].y - m) * rs * g.y + b.y;
      float a2 = (xr[i].z - m) * rs * g.z + b.z;
      float a3 = (xr[i].w - m) * rs * g.w + b.w;
      dst[i*2+0] = (unsigned)f2bf(a0) | ((unsigned)f2bf(a1) << 16);
      dst[i*2+1] = (unsigned)f2bf(a2) | ((unsigned)f2bf(a3) << 16);
    }
  }
  __syncthreads();

  // Phase D: QKV A-fragments (wave w rows w*16+lm) into regs
  bf16x8 af[3];
  #pragma unroll
  for (int ks = 0; ks < 3; ++ks)
    af[ks] = *(const bf16x8*)&xob_s[(w * 16 + lm) * 104 + ks * 32 + lg * 8];
  __syncthreads();   // xob consumed (as input) before ob writes later

  // Phase E: QKV MFMA. Wave w: rows [16w,16w+16), all 288 cols.
  // q,k -> bf16 row buffers; v -> bf16 TRANSPOSED (vtb[d][m]).
  #pragma unroll
  for (int nt = 0; nt < 18; ++nt) {
    const int j = nt * 16 + lm;
    bf16x8 b0 = *(const bf16x8*)&qkvwb[j * 96 + 0  + lg * 8];
    bf16x8 b1 = *(const bf16x8*)&qkvwb[j * 96 + 32 + lg * 8];
    bf16x8 b2 = *(const bf16x8*)&qkvwb[j * 96 + 64 + lg * 8];
    f32x4 acc = {0.f, 0.f, 0.f, 0.f};
    acc = __builtin_amdgcn_mfma_f32_16x16x32_bf16(af[0], b0, acc, 0, 0, 0);
    acc = __builtin_amdgcn_mfma_f32_16x16x32_bf16(af[1], b1, acc, 0, 0, 0);
    acc = __builtin_amdgcn_mfma_f32_16x16x32_bf16(af[2], b2, acc, 0, 0, 0);
    const float bias = qkv_b[j];
    #pragma unroll
    for (int qq = 0; qq < 4; ++qq) {
      const int r2 = w * 16 + lg * 4 + qq;     // token row
      float val = acc[qq] + bias;
      if (j < 96)       qb_s[r2 * 104 + j] = f2bf(val * SCALE);
      else if (j < 192) kb_s[r2 * 104 + (j - 96)] = f2bf(val);
      else              vtb_s[(j - 192) * 72 + r2] = f2bf(val);
    }
  }
  __syncthreads();

  // Phase F: attention strips. 12 strips = 3 heads x 4 row-tiles; wave w does
  // strips {w, w+4, w+8}. Per strip: QK^T (4 MFMA) -> +mask+bias -> softmax
  // (shfl over lm) -> P bf16 -> LDS transpose -> PV (4 MFMA) -> ob bf16.
  #pragma unroll
  for (int s3 = 0; s3 < 3; ++s3) {
    const int strip = w + s3 * 4;
    const int h  = strip >> 2;         // head 0..2
    const int rt = strip & 3;          // row-tile 0..3
    const int hoff = h * 32;

    bf16x8 aq = *(const bf16x8*)&qb_s[(rt * 16 + lm) * 104 + hoff + lg * 8];
    f32x4 sacc[4];
    #pragma unroll
    for (int ct = 0; ct < 4; ++ct) {
      bf16x8 bk = *(const bf16x8*)&kb_s[(ct * 16 + lm) * 104 + hoff + lg * 8];
      f32x4 z = {0.f, 0.f, 0.f, 0.f};
      sacc[ct] = __builtin_amdgcn_mfma_f32_16x16x32_bf16(aq, bk, z, 0, 0, 0);
    }

    // bias + mask in D-layout; rows r_loc=4*lg+q, cols ct*16+lm
    float sv[4][4];   // [q][ct]
    const int rbase = rt * 16 + lg * 4;
    #pragma unroll
    for (int qq = 0; qq < 4; ++qq) {
      const float* mrow = mask + (wi * 64 + rbase + qq) * 64;
      const float* brow = biasf + h * 4096 + (rbase + qq) * 64;
      #pragma unroll
      for (int ct = 0; ct < 4; ++ct) {
        int cg = ct * 16 + lm;
        sv[qq][ct] = sacc[ct][qq] + mrow[cg] + brow[cg];
      }
    }
    // softmax per row (reduce over 4 ct locally + 16 lm lanes via shfl)
    #pragma unroll
    for (int qq = 0; qq < 4; ++qq) {
      float mx = fmaxf(fmaxf(sv[qq][0], sv[qq][1]), fmaxf(sv[qq][2], sv[qq][3]));
      mx = fmaxf(mx, __shfl_xor(mx, 1));
      mx = fmaxf(mx, __shfl_xor(mx, 2));
      mx = fmaxf(mx, __shfl_xor(mx, 4));
      mx = fmaxf(mx, __shfl_xor(mx, 8));
      float e0 = __expf(sv[qq][0] - mx), e1 = __expf(sv[qq][1] - mx);
      float e2 = __expf(sv[qq][2] - mx), e3 = __expf(sv[qq][3] - mx);
      float sum = e0 + e1 + e2 + e3;
      sum += __shfl_xor(sum, 1);
      sum += __shfl_xor(sum, 2);
      sum += __shfl_xor(sum, 4);
      sum += __shfl_xor(sum, 8);
      float inv = 1.0f / sum;
      // write P row (strip-local row lg*4+q) into per-wave buffer
      unsigned short* prow = pb_s + (w * 16 + lg * 4 + qq) * 72;
      prow[0  + lm] = f2bf(e0 * inv);
      prow[16 + lm] = f2bf(e1 * inv);
      prow[32 + lm] = f2bf(e2 * inv);
      prow[48 + lm] = f2bf(e3 * inv);
    }
    __syncthreads();   // P visible cross-lane (and ordered vs prior iter)

    // PV: A = P (rows lm of this strip), B = V^T slice; K = 64 tokens (2 ks)
    bf16x8 pa0 = *(const bf16x8*)&pb_s[(w * 16 + lm) * 72 + 0  + lg * 8];
    bf16x8 pa1 = *(const bf16x8*)&pb_s[(w * 16 + lm) * 72 + 32 + lg * 8];
    #pragma unroll
    for (int nt = 0; nt < 2; ++nt) {
      const int dcol = hoff + nt * 16 + lm;    // output head-dim col
      bf16x8 bv0 = *(const bf16x8*)&vtb_s[dcol * 72 + 0  + lg * 8];
      bf16x8 bv1 = *(const bf16x8*)&vtb_s[dcol * 72 + 32 + lg * 8];
      f32x4 z = {0.f, 0.f, 0.f, 0.f};
      f32x4 oacc = __builtin_amdgcn_mfma_f32_16x16x32_bf16(pa0, bv0, z, 0, 0, 0);
      oacc = __builtin_amdgcn_mfma_f32_16x16x32_bf16(pa1, bv1, oacc, 0, 0, 0);
      #pragma unroll
      for (int qq = 0; qq < 4; ++qq)
        xob_s[(rt * 16 + lg * 4 + qq) * 104 + dcol] = f2bf(oacc[qq]);
    }
    __syncthreads();   // ob writes done; pb safe to overwrite next strip
  }

  // Phase G: proj MFMA + bias + shortcut -> x2 (f32 in d_out).
  bf16x8 ao[3];
  #pragma unroll
  for (int ks = 0; ks < 3; ++ks)
    ao[ks] = *(const bf16x8*)&xob_s[(w * 16 + lm) * 104 + ks * 32 + lg * 8];

  #pragma unroll
  for (int nt = 0; nt < 6; ++nt) {
    const int j = nt * 16 + lm;
    bf16x8 b0 = *(const bf16x8*)&projwb[j * 96 + 0  + lg * 8];
    bf16x8 b1 = *(const bf16x8*)&projwb[j * 96 + 32 + lg * 8];
    bf16x8 b2 = *(const bf16x8*)&projwb[j * 96 + 64 + lg * 8];
    f32x4 acc = {0.f, 0.f, 0.f, 0.f};
    acc = __builtin_amdgcn_mfma_f32_16x16x32_bf16(ao[0], b0, acc, 0, 0, 0);
    acc = __builtin_amdgcn_mfma_f32_16x16x32_bf16(ao[1], b1, acc, 0, 0, 0);
    acc = __builtin_amdgcn_mfma_f32_16x16x32_bf16(ao[2], b2, acc, 0, 0, 0);
    const float bias = proj_b[j];
    #pragma unroll
    for (int qq = 0; qq < 4; ++qq) {
      const int r2 = w * 16 + lg * 4 + qq;
      const int l  = lidx[r2];
      x2[l * 96 + j] = x[l * 96 + j] + acc[qq] + bias;
    }
  }
}

// ---------------------------------------------------------------------------
// Kernel 2: MFMA MLP, 32 rows/block (4608 blocks), LDS 31.7KB -> ~5 blocks/CU.
// LN2 fully in-register (8 lanes/row shfl). fc1 jobs: 2mt x {6 nt per wave};
// fc2 jobs: wave w does {w, w+4, w+8} of 12 (rt x nt). tanh-GELU.
// In-place residual on d_out (all reads precede the single write per elem).
// ---------------------------------------------------------------------------
__global__ __launch_bounds__(256) void k_mlp(
    float* __restrict__ x2,                     // [147456,96] f32 = d_out
    const float* __restrict__ n2g, const float* __restrict__ n2b,
    const float* __restrict__ fc1b, const float* __restrict__ fc2b,
    const unsigned short* __restrict__ fc1wb,   // [384,96] bf16
    const unsigned short* __restrict__ fc2wb)   // [96,384] bf16
{
  __shared__ unsigned short xnb[32 * 104];
  __shared__ unsigned short hid[32 * 392];

  const int tid  = threadIdx.x;
  const int R0   = blockIdx.x * 32;
  const int lane = tid & 63;
  const int w    = tid >> 6;
  const int lm   = lane & 15, lg = lane >> 4;

  // LN2: thread (r=tid>>3, qq=tid&7) owns 12 cols; stats via 8-lane shfl.
  {
    const int r = tid >> 3, qq = tid & 7;
    const float4* px = (const float4*)(x2 + (R0 + r) * 96 + qq * 12);
    float4 xr[3];
    float s = 0.f, s2 = 0.f;
    #pragma unroll
    for (int i = 0; i < 3; ++i) {
      xr[i] = px[i];
      s  += xr[i].x + xr[i].y + xr[i].z + xr[i].w;
      s2 += xr[i].x*xr[i].x + xr[i].y*xr[i].y + xr[i].z*xr[i].z + xr[i].w*xr[i].w;
    }
    s += __shfl_xor(s, 1); s2 += __shfl_xor(s2, 1);
    s += __shfl_xor(s, 2); s2 += __shfl_xor(s2, 2);
    s += __shfl_xor(s, 4); s2 += __shfl_xor(s2, 4);
    float m   = s * (1.0f / 96.0f);
    float var = s2 * (1.0f / 96.0f) - m * m;
    float rs  = rsqrtf(var + 1e-5f);
    const float4* pg = (const float4*)(n2g + qq * 12);
    const float4* pb = (const float4*)(n2b + qq * 12);
    unsigned* dst = (unsigned*)xnb + r * 52 + qq * 6;
    #pragma unroll
    for (int i = 0; i < 3; ++i) {
      float4 g = pg[i], b = pb[i];
      float a0 = (xr[i].x - m) * rs * g.x + b.x;
      float a1 = (xr[i].y - m) * rs * g.y + b.y;
      float a2 = (xr[i].z - m) * rs * g.z + b.z;
      float a3 = (xr[i].w - m) * rs * g.w + b.w;
      dst[i*2+0] = (unsigned)f2bf(a0) | ((unsigned)f2bf(a1) << 16);
      dst[i*2+1] = (unsigned)f2bf(a2) | ((unsigned)f2bf(a3) << 16);
    }
  }
  __syncthreads();

  // fc1 (+bias, tanh-GELU) -> hid bf16. Jobs: mt in {0,1} x nt = w+4*jjj.
  #pragma unroll
  for (int mt = 0; mt < 2; ++mt) {
    bf16x8 a0 = *(const bf16x8*)&xnb[(mt * 16 + lm) * 104 + 0  + lg * 8];
    bf16x8 a1 = *(const bf16x8*)&xnb[(mt * 16 + lm) * 104 + 32 + lg * 8];
    bf16x8 a2 = *(const bf16x8*)&xnb[(mt * 16 + lm) * 104 + 64 + lg * 8];
    #pragma unroll
    for (int jjj = 0; jjj < 6; ++jjj) {
      const int nt = w + 4 * jjj;             // 0..23
      const int j  = nt * 16 + lm;            // hidden col 0..383
      bf16x8 b0 = *(const bf16x8*)&fc1wb[j * 96 + 0  + lg * 8];
      bf16x8 b1 = *(const bf16x8*)&fc1wb[j * 96 + 32 + lg * 8];
      bf16x8 b2 = *(const bf16x8*)&fc1wb[j * 96 + 64 + lg * 8];
      f32x4 acc = {0.f, 0.f, 0.f, 0.f};
      acc = __builtin_amdgcn_mfma_f32_16x16x32_bf16(a0, b0, acc, 0, 0, 0);
      acc = __builtin_amdgcn_mfma_f32_16x16x32_bf16(a1, b1, acc, 0, 0, 0);
      acc = __builtin_amdgcn_mfma_f32_16x16x32_bf16(a2, b2, acc, 0, 0, 0);
      const float bias = fc1b[j];
      #pragma unroll
      for (int qq = 0; qq < 4; ++qq) {
        float h = acc[qq] + bias;
        // tanh-GELU: 0.5h(1+tanh(0.79788456(h+0.044715h^3)))
        float y = 0.79788456080286536f * (h + 0.044715f * h * h * h);
        float t = 1.0f - 2.0f / (__expf(2.0f * y) + 1.0f);
        float g = 0.5f * h * (1.0f + t);
        hid[(mt * 16 + lg * 4 + qq) * 392 + j] = f2bf(g);
      }
    }
  }
  __syncthreads();

  // fc2 (+bias, +residual in-place). Jobs {w, w+4, w+8}: rt = job/6, nt = job%6.
  #pragma unroll
  for (int jj = 0; jj < 3; ++jj) {
    const int job = w + 4 * jj;               // 0..11
    const int rt  = job / 6, nt = job % 6;
    const int j   = nt * 16 + lm;             // out col 0..95
    f32x4 acc = {0.f, 0.f, 0.f, 0.f};
    #pragma unroll
    for (int ks = 0; ks < 12; ++ks) {
      bf16x8 a = *(const bf16x8*)&hid[(rt * 16 + lm) * 392 + ks * 32 + lg * 8];
      bf16x8 b = *(const bf16x8*)&fc2wb[j * 384 + ks * 32 + lg * 8];
      acc = __builtin_amdgcn_mfma_f32_16x16x32_bf16(a, b, acc, 0, 0, 0);
    }
    const float bias = fc2b[j];
    #pragma unroll
    for (int qq = 0; qq < 4; ++qq) {
      int row = R0 + rt * 16 + lg * 4 + qq;
      x2[row * 96 + j] = acc[qq] + bias + x2[row * 96 + j];
    }
  }
}

extern "C" void kernel_launch(void* const* d_in, const int* in_sizes, int n_in,
                              void* d_out, int out_size, void* d_ws, size_t ws_size,
                              hipStream_t stream) {
  const float* x      = (const float*)d_in[0];
  const float* mask   = (const float*)d_in[1];
  const int*   relidx = (const int*)d_in[2];
  const float* qkv_w  = (const float*)d_in[3];
  const float* qkv_b  = (const float*)d_in[4];
  const float* proj_w = (const float*)d_in[5];
  const float* proj_b = (const float*)d_in[6];
  const float* n1g    = (const float*)d_in[7];
  const float* n1b    = (const float*)d_in[8];
  const float* n2g    = (const float*)d_in[9];
  const float* n2b    = (const float*)d_in[10];
  const float* fc1w   = (const float*)d_in[11];
  const float* fc1b   = (const float*)d_in[12];
  const float* fc2w   = (const float*)d_in[13];
  const float* fc2b   = (const float*)d_in[14];
  const float* rpb    = (const float*)d_in[15];

  // ws layout (270,336 B total): wtb bf16 [110592 shorts] | biasf f32 [12288]
  unsigned short* wtb = (unsigned short*)d_ws;                 // 221,184 B
  float* biasf = (float*)((char*)d_ws + 221184);               // 49,152 B
  float* x2 = (float*)d_out;                                   // f32 residual & final out

  k_cvt<<<dim3(264), dim3(256), 0, stream>>>(
      fc1w, fc2w, qkv_w, proj_w, relidx, rpb, (unsigned*)wtb, biasf);
  k_attn<<<dim3(2304), dim3(256), 0, stream>>>(
      x, mask, qkv_b, proj_b, n1g, n1b,
      wtb + 73728 /*qkvwb*/, wtb + 101376 /*projwb*/, biasf, x2);
  k_mlp<<<dim3(4608), dim3(256), 0, stream>>>(
      x2, n2g, n2b, fc1b, fc2b,
      wtb /*fc1wb*/, wtb + 36864 /*fc2wb*/);
}